// Round 7
// baseline (263.568 us; speedup 1.0000x reference)
//
#include <hip/hip_runtime.h>
#include <hip/hip_bf16.h>

using uint32   = unsigned int;
using ushort_t = unsigned short;
using short8   = __attribute__((ext_vector_type(8))) short;
using uint4v   = __attribute__((ext_vector_type(4))) uint32;
using floatx16 = __attribute__((ext_vector_type(16))) float;

#define M_DIM 32
#define K_DIM 8192
#define N_DIM 28672
#define QROW  (N_DIM/8)   /* 3584 dwords per qweight k-row */
#define KSPLIT 8
#define BN    128         /* n per block; 32 n per wave */
#define CH    128         /* k per chunk == QGS */
#define NCH   8           /* chunks per block (1024 k) */

__device__ ushort_t g_xr2[M_DIM * K_DIM]; // rotated x, k-octet-major MFMA-A order
__device__ float    g_S[64 * M_DIM];      // per-group row sums of bf16(xr)

__device__ __forceinline__ float bf2f(ushort_t u){
  unsigned int v = ((unsigned int)u) << 16;
  return __builtin_bit_cast(float, v);
}
__device__ __forceinline__ ushort_t f2bf(float f){
  return __builtin_bit_cast(ushort_t, __float2bfloat16(f)); // RNE
}

// ---------------- rotation + group sums --------------------------------
// one 64-lane unit per (m, g). Output layout: element (m,k) ->
// g_xr2[((k>>3)*32 + m)*8 + (k&7)]  (contiguous per-octet A slices).
__global__ __launch_bounds__(256) void rotate_kernel(
    const float* __restrict__ x, const float* __restrict__ theta,
    const int* __restrict__ pairs, const float* __restrict__ cs)
{
  __shared__ float xb[4][128];
  const int u    = threadIdx.x >> 6;
  const int lane = threadIdx.x & 63;
  const int id   = blockIdx.x * 4 + u;   // 0..2047 = m*64+g
  const int m    = id >> 6;
  const int g    = id & 63;
  const float* xp = x + m*K_DIM + g*128;
  int   ip[8], jp[8];
  float cv[8], sv[8];
  #pragma unroll
  for (int k = 0; k < 8; ++k){
    ip[k] = pairs[k*128 + 2*lane];
    jp[k] = pairs[k*128 + 2*lane + 1];
    const float th = theta[k*(K_DIM/2) + g*64 + lane];
    cv[k] = cosf(th); sv[k] = sinf(th);
  }
  xb[u][lane]    = xp[lane];
  xb[u][lane+64] = xp[lane+64];
  #pragma unroll
  for (int k = 0; k < 8; ++k){
    __syncthreads();
    const float xi = xb[u][ip[k]], xj = xb[u][jp[k]];
    xb[u][ip[k]] = cv[k]*xi - sv[k]*xj;
    xb[u][jp[k]] = sv[k]*xi + cv[k]*xj;
  }
  __syncthreads();
  const int base = g*128;
  const int k0 = base + lane, k1 = base + lane + 64;
  const ushort_t b0 = f2bf(xb[u][lane]    * cs[k0]);
  const ushort_t b1 = f2bf(xb[u][lane+64] * cs[k1]);
  g_xr2[(((size_t)(k0>>3))*32 + m)*8 + (k0&7)] = b0;
  g_xr2[(((size_t)(k1>>3))*32 + m)*8 + (k1&7)] = b1;
  float sum = bf2f(b0) + bf2f(b1);
  #pragma unroll
  for (int d = 32; d > 0; d >>= 1) sum += __shfl_xor(sum, d, 64);
  if (lane == 0) g_S[g*M_DIM + m] = sum;
}

// ------------- init2: out = bias - sum_g s*(128+z)*S_g -----------------
__global__ __launch_bounds__(256) void init2_kernel(
    const uint32* __restrict__ qz, const float* __restrict__ scales,
    const float* __restrict__ bias, float* __restrict__ out)
{
  const int n = blockIdx.x*256 + threadIdx.x;
  const uint32 sh = (uint32)((n & 7)*4);
  float acc[M_DIM];
  const float b = bias[n];
  #pragma unroll
  for (int m = 0; m < M_DIM; ++m) acc[m] = b;
  #pragma unroll 1
  for (int g = 0; g < 64; ++g){
    const float s  = scales[(size_t)g*N_DIM + n];
    const uint32 zq = qz[(size_t)g*QROW + (n>>3)];
    const float t  = s * (float)(128u + ((zq >> sh) & 15u));
    #pragma unroll
    for (int m = 0; m < M_DIM; ++m)
      acc[m] = fmaf(-t, g_S[g*M_DIM + m], acc[m]);
  }
  #pragma unroll
  for (int m = 0; m < M_DIM; ++m) out[(size_t)m*N_DIM + n] = acc[m];
}

// ---- barrier-free GEMM: wave-private B staging w/ register transpose ----
// grid 1792 = (N/128) x KSPLIT, 256 threads (4 waves). Each wave: 32 n,
// 1024 k. Per chunk(128k): 8 coalesced b32 B-loads/thread -> 8x8 nibble
// transpose in regs -> 8 ds_write -> 2 ds_read_b128/lane -> 8 MFMA.
__global__ __launch_bounds__(256, 4) void gemm_kernel(
    const uint32* __restrict__ qw, const float* __restrict__ scales,
    float* __restrict__ out)
{
  __shared__ uint32 T2[4][2][32*17];     // per-wave, dbuf, 17.4 KB total
  const int bid  = blockIdx.x;
  const int ks   = bid & 7;
  const int nb   = bid >> 3;
  const int w    = (threadIdx.x) >> 6;
  const int lane = threadIdx.x & 63;
  const int l31  = lane & 31;
  const int koct = lane >> 5;
  const int n0   = nb * BN;
  const int n    = n0 + w*32 + l31;
  const int k0   = ks * (NCH*CH);

  // B staging map: lane covers col (lane&3) of wave slice, rows rb..rb+7
  const int bl_col = lane & 3;
  const int bl_rb  = (lane >> 2) * 8;             // 0..120 step 8
  const int cw0    = (n0 + w*32) >> 3;            // wave's first dword-col
  const uint32* bbase = qw + (size_t)(k0 + bl_rb)*QROW + cw0 + bl_col;
  // T2 write indices: nl = (lane&3)*8 + j, octet o = lane>>2: koct=o&1, kk=o>>3? no: kk=o>>1
  const int wr_koct = (lane >> 2) & 1;
  const int wr_kk   = lane >> 3;
  uint32* Tw = &T2[w][0][0];

  const int base_o = k0 >> 3;                     // A octet base

  float accT[16];
  #pragma unroll
  for (int r = 0; r < 16; ++r) accT[r] = 0.f;

  uint32 d[8];

  auto loadB = [&](int c){
    const uint32* bp = bbase + (size_t)c*CH*QROW;
    #pragma unroll
    for (int i = 0; i < 8; ++i) d[i] = bp[(size_t)i*QROW];
  };
  auto transposeWrite = [&](int c){
    // 8x8 nibble transpose: element(i,j): d[i] nibble j -> d[j] nibble i
    #pragma unroll
    for (int s = 0; s < 3; ++s){
      const int st = 1 << s, sh4 = 4 << s;
      const uint32 M = (s==0) ? 0x0F0F0F0Fu : (s==1) ? 0x00FF00FFu : 0x0000FFFFu;
      #pragma unroll
      for (int i = 0; i < 8; ++i){
        if (i & st) continue;
        const uint32 t = ((d[i] >> sh4) ^ d[i+st]) & M;
        d[i]    ^= t << sh4;
        d[i+st] ^= t;
      }
    }
    uint32* tb = Tw + (c & 1)*(32*17);
    #pragma unroll
    for (int j = 0; j < 8; ++j)
      tb[(bl_col*8 + j)*17 + wr_koct*8 + wr_kk] = d[j];
  };

  loadB(0);
  transposeWrite(0);

  #pragma unroll 1
  for (int c = 0; c < NCH; ++c){
    const uint32* tb = Tw + (c & 1)*(32*17) + l31*17 + koct*8;
    const uint4v rd0 = *(const uint4v*)(tb);
    const uint4v rd1 = *(const uint4v*)(tb + 4);
    if (c + 1 < NCH) loadB(c + 1);
    const float s = scales[(size_t)(ks*NCH + c)*N_DIM + n];

    floatx16 acc;
    #pragma unroll
    for (int r = 0; r < 16; ++r) acc[r] = 0.f;
    #pragma unroll
    for (int kk = 0; kk < 8; ++kk){
      const int o = base_o + c*16 + kk*2 + koct;  // A octet index
      const short8 a = *(const short8*)(g_xr2 + (size_t)o*256 + l31*8);
      const uint32 q = (kk < 4) ? rd0[kk] : rd1[kk - 4];
      uint4v bp;
      bp.x = ( q        & 15u) | (((q >>  4) & 15u) << 16) | 0x43004300u;
      bp.y = ((q >>  8) & 15u) | (((q >> 12) & 15u) << 16) | 0x43004300u;
      bp.z = ((q >> 16) & 15u) | (((q >> 20) & 15u) << 16) | 0x43004300u;
      bp.w = ((q >> 24) & 15u) | ( (q >> 28)        << 16) | 0x43004300u;
      acc = __builtin_amdgcn_mfma_f32_32x32x16_bf16(
                a, __builtin_bit_cast(short8, bp), acc, 0, 0, 0);
    }
    #pragma unroll
    for (int r = 0; r < 16; ++r) accT[r] = fmaf(s, acc[r], accT[r]);
    if (c + 1 < NCH) transposeWrite(c + 1);
  }
  // C/D layout (HW-verified m74/m101): col=lane&31, row=(r&3)+8*(r>>2)+4*koct
  #pragma unroll
  for (int r = 0; r < 16; ++r){
    const int row = (r & 3) + 8*(r >> 2) + 4*koct;
    atomicAdd(out + (size_t)row*N_DIM + n, accT[r]);
  }
}

extern "C" void kernel_launch(void* const* d_in, const int* in_sizes, int n_in,
                              void* d_out, int out_size, void* d_ws, size_t ws_size,
                              hipStream_t stream)
{
  const float*  x      = (const float*)d_in[0];
  const uint32* qw     = (const uint32*)d_in[1];
  const uint32* qz     = (const uint32*)d_in[2];
  const float*  scales = (const float*)d_in[3];
  const float*  bias   = (const float*)d_in[4];
  const float*  theta  = (const float*)d_in[5];
  const int*    pairs  = (const int*)d_in[6];
  const float*  cs     = (const float*)d_in[7];
  float* out = (float*)d_out;

  rotate_kernel<<<dim3((M_DIM*64)/4), dim3(256), 0, stream>>>(x, theta, pairs, cs);
  init2_kernel<<<dim3(N_DIM/256), dim3(256), 0, stream>>>(qz, scales, bias, out);
  gemm_kernel<<<dim3((N_DIM/BN)*KSPLIT), dim3(256), 0, stream>>>(qw, scales, out);
}